// Round 1
// baseline (470.916 us; speedup 1.0000x reference)
//
#include <hip/hip_runtime.h>
#include <hip/hip_bf16.h>

// Problem constants (from reference)
#define BATCH   512
#define INCH    20
#define HDIM    32
#define WDIM    32
#define FEAT    128
#define NAGENT  4
#define KACT    16
#define NUNIT   12

// Fused: conv3x3(SAME) + bias + relu + mask, then per-sample head GEMM
// (W_all[labels[b]]) producing out[b, y, x, 16], split into (..12) and (12..16).
// One block per batch sample; 256 threads; padded input staged in LDS.
__global__ __launch_bounds__(256) void fused_fp32_kernel(
    const float* __restrict__ states,    // [B, 20, 32, 32]
    const int*   __restrict__ labels,    // [B]
    const float* __restrict__ maskings,  // [B, 1, 32, 32]
    const float* __restrict__ conv_w,    // [128, 20, 3, 3]
    const float* __restrict__ conv_b,    // [128]
    const float* __restrict__ W_all,     // [4, 16, 128]
    const float* __restrict__ b_all,     // [4, 16]
    float*       __restrict__ out)       // [B*1024*12] then [B*1024*4]
{
    const int b   = blockIdx.x;
    const int tid = threadIdx.x;

    __shared__ float sIn[INCH][34][34];   // zero-padded input, 92,480 B
    __shared__ float sW[KACT][FEAT];      // selected head weights
    __shared__ float sB[KACT];            // selected head bias
    __shared__ float sCB[FEAT];           // conv bias

    // ---- Stage padded input (zero border) ----
    for (int idx = tid; idx < INCH * 34 * 34; idx += 256) {
        int c = idx / (34 * 34);
        int r = idx - c * (34 * 34);
        int y = r / 34;
        int x = r - y * 34;
        float v = 0.0f;
        if (y >= 1 && y <= 32 && x >= 1 && x <= 32) {
            v = states[((b * INCH + c) * 32 + (y - 1)) * 32 + (x - 1)];
        }
        sIn[c][y][x] = v;
    }

    // ---- Gather this sample's head params ----
    const int label = labels[b];
    for (int idx = tid; idx < KACT * FEAT; idx += 256) {
        sW[idx / FEAT][idx % FEAT] = W_all[label * (KACT * FEAT) + idx];
    }
    if (tid < KACT) sB[tid]  = b_all[label * KACT + tid];
    if (tid < FEAT) sCB[tid] = conv_b[tid];
    __syncthreads();

    // Each thread owns 4 output positions: column x, rows ybase..ybase+3.
    const int x     = tid & 31;
    const int ybase = (tid >> 5) * 4;

    float mk[4];
    #pragma unroll
    for (int i = 0; i < 4; ++i) {
        mk[i] = maskings[(b * 32 + (ybase + i)) * 32 + x];
    }

    float acc[4][KACT];
    #pragma unroll
    for (int i = 0; i < 4; ++i)
        #pragma unroll
        for (int k = 0; k < KACT; ++k)
            acc[i][k] = 0.0f;

    // ---- Conv + head, streaming feature channels in chunks of 8 ----
    for (int f0 = 0; f0 < FEAT; f0 += 8) {
        float xa[4][8];
        #pragma unroll
        for (int i = 0; i < 4; ++i)
            #pragma unroll
            for (int j = 0; j < 8; ++j)
                xa[i][j] = 0.0f;

        for (int c = 0; c < INCH; ++c) {
            // 6 rows x 3 cols register window serves 4 vertical positions
            float v[6][3];
            #pragma unroll
            for (int r = 0; r < 6; ++r)
                #pragma unroll
                for (int cc = 0; cc < 3; ++cc)
                    v[r][cc] = sIn[c][ybase + r][x + cc];

            #pragma unroll
            for (int f8 = 0; f8 < 8; ++f8) {
                const float* wp = conv_w + ((f0 + f8) * INCH + c) * 9;  // uniform -> s_load
                #pragma unroll
                for (int ky = 0; ky < 3; ++ky) {
                    #pragma unroll
                    for (int kx = 0; kx < 3; ++kx) {
                        float w = wp[ky * 3 + kx];
                        xa[0][f8] = fmaf(v[0 + ky][kx], w, xa[0][f8]);
                        xa[1][f8] = fmaf(v[1 + ky][kx], w, xa[1][f8]);
                        xa[2][f8] = fmaf(v[2 + ky][kx], w, xa[2][f8]);
                        xa[3][f8] = fmaf(v[3 + ky][kx], w, xa[3][f8]);
                    }
                }
            }
        }

        // Finish features: bias + relu + mask, accumulate head GEMM
        #pragma unroll
        for (int f8 = 0; f8 < 8; ++f8) {
            const int f = f0 + f8;
            const float cb = sCB[f];
            #pragma unroll
            for (int i = 0; i < 4; ++i) {
                float xv = fmaxf(xa[i][f8] + cb, 0.0f) * mk[i];
                #pragma unroll
                for (int k = 0; k < KACT; ++k) {
                    acc[i][k] = fmaf(xv, sW[k][f], acc[i][k]);
                }
            }
        }
    }

    // ---- Write split outputs ----
    const long out2_base = (long)BATCH * 1024 * NUNIT;  // 6,291,456
    #pragma unroll
    for (int i = 0; i < 4; ++i) {
        const int y = ybase + i;
        const long pos = ((long)b * 32 + y) * 32 + x;
        float* o1 = out + pos * NUNIT;
        float* o2 = out + out2_base + pos * (KACT - NUNIT);
        #pragma unroll
        for (int k = 0; k < NUNIT; ++k) o1[k] = acc[i][k] + sB[k];
        #pragma unroll
        for (int k = 0; k < KACT - NUNIT; ++k) o2[k] = acc[i][NUNIT + k] + sB[NUNIT + k];
    }
}

extern "C" void kernel_launch(void* const* d_in, const int* in_sizes, int n_in,
                              void* d_out, int out_size, void* d_ws, size_t ws_size,
                              hipStream_t stream) {
    const float* states   = (const float*)d_in[0];
    const int*   labels   = (const int*)d_in[1];
    const float* maskings = (const float*)d_in[2];
    const float* conv_w   = (const float*)d_in[3];
    const float* conv_b   = (const float*)d_in[4];
    const float* W_all    = (const float*)d_in[5];
    const float* b_all    = (const float*)d_in[6];
    float* out = (float*)d_out;

    fused_fp32_kernel<<<BATCH, 256, 0, stream>>>(
        states, labels, maskings, conv_w, conv_b, W_all, b_all, out);
}

// Round 2
// 64.063 us; speedup vs baseline: 7.3508x; 7.3508x over previous
//
#include <hip/hip_runtime.h>
#include <hip/hip_bf16.h>
#include <stdint.h>

#define BATCH   512
#define INCH    20
#define FEAT    128
#define KACT    16
#define NUNIT   12

typedef short bf16x8 __attribute__((ext_vector_type(8)));
typedef float f32x4  __attribute__((ext_vector_type(4)));

#define BPACK_ELEMS (3*2*4*128*8)   // 24576 bf16: [ky][kk][g][f][j], k = kk*32+g*8+j -> (kx=k/20, c=k%20), 0 for k>=60
#define WHEAD_ELEMS (4*4*4*16*8)    // 8192 bf16:  [agent][kt][g][action][j], f = kt*32+g*8+j

#define XIN_ELEMS   (34*34*20 + 48) // padded input [yy][xx][c] bf16 + slack (slack stays zero)
#define XLDS_STRIDE 136             // x tile [128 p][136] bf16 (pad 8 -> 16B-aligned rows, 2-way banks)

__device__ __forceinline__ uint16_t f2bf(float f) {
    union { float f; uint32_t u; } x{f};
    uint32_t u = x.u;
    return (uint16_t)((u + 0x7FFFu + ((u >> 16) & 1u)) >> 16);  // RNE
}

// ---- One-time weight repack (fp32 -> bf16 fragment order) ----
__global__ void repack_kernel(const float* __restrict__ conv_w,
                              const float* __restrict__ W_all,
                              uint16_t* __restrict__ Bpack,
                              uint16_t* __restrict__ Whead) {
    int idx = blockIdx.x * 256 + threadIdx.x;
    if (idx < BPACK_ELEMS) {
        int j = idx & 7, t = idx >> 3;
        int f = t & 127; t >>= 7;
        int g = t & 3;   t >>= 2;
        int kk = t & 1;  int ky = t >> 1;
        int k = kk * 32 + g * 8 + j;
        float v = 0.0f;
        if (k < 60) {
            int kx = k / 20, c = k % 20;
            v = conv_w[((f * INCH + c) * 3 + ky) * 3 + kx];
        }
        Bpack[idx] = f2bf(v);
    } else if (idx < BPACK_ELEMS + WHEAD_ELEMS) {
        int i = idx - BPACK_ELEMS;
        int j = i & 7, t = i >> 3;
        int a = t & 15; t >>= 4;
        int g = t & 3;  t >>= 2;
        int kt = t & 3; int ag = t >> 2;
        int f = kt * 32 + g * 8 + j;
        Whead[i] = f2bf(W_all[(ag * KACT + a) * FEAT + f]);
    }
}

// ---- Fused conv3x3 + relu/bias/mask + per-sample head GEMM, all MFMA ----
__global__ __launch_bounds__(256, 2) void fused_mfma_kernel(
    const float* __restrict__ states,    // [512,20,32,32]
    const int*   __restrict__ labels,    // [512]
    const float* __restrict__ maskings,  // [512,1,32,32]
    const float* __restrict__ conv_b,    // [128]
    const float* __restrict__ b_all,     // [4,16]
    const uint16_t* __restrict__ Bpack,
    const uint16_t* __restrict__ Whead,
    float*       __restrict__ out)       // [512*1024*12] ++ [512*1024*4]
{
    __shared__ __align__(16) uint16_t xin[XIN_ELEMS];       // 46,336 B
    __shared__ __align__(16) uint16_t xlds[128 * XLDS_STRIDE]; // 34,816 B

    const int b    = blockIdx.x;
    const int tid  = threadIdx.x;
    const int lane = tid & 63;
    const int w    = tid >> 6;     // 4 waves
    const int l15  = lane & 15;
    const int g    = lane >> 4;    // 0..3
    const int mtq  = w >> 1;       // conv: wave owns mtiles mtq*4..+3 of the chunk
    const int ntq  = w & 1;        // conv: wave owns ntiles ntq*4..+3 (features ntq*64..+63)

    // ---- zero xin (incl. slack) ----
    {
        uint32_t* p = (uint32_t*)xin;
        for (int i = tid; i < XIN_ELEMS / 2; i += 256) p[i] = 0;
    }
    __syncthreads();

    // ---- stage input: states[c][y][x] fp32 -> xin[(y+1)*34 + (x+1)]*20 + c (bf16) ----
    {
        const float4* sp = (const float4*)(states + (size_t)b * INCH * 1024);
        for (int i = tid; i < INCH * 256; i += 256) {
            int c  = i >> 8;
            int r  = i & 255;
            int y  = r >> 3;
            int x4 = (r & 7) << 2;
            float4 v = sp[i];
            uint16_t* d = &xin[((y + 1) * 34 + (x4 + 1)) * 20 + c];
            d[0]  = f2bf(v.x);
            d[20] = f2bf(v.y);
            d[40] = f2bf(v.z);
            d[60] = f2bf(v.w);
        }
    }

    // ---- per-lane invariants ----
    const int label = labels[b];
    float cb[4];
    #pragma unroll
    for (int nt = 0; nt < 4; ++nt) cb[nt] = conv_b[ntq * 64 + nt * 16 + l15];
    const float hbias = b_all[label * KACT + l15];

    bf16x8 Bc[3][2][4];   // conv B-frags [ky][kk][nt] : 96 VGPRs, kernel-invariant
    #pragma unroll
    for (int ky = 0; ky < 3; ++ky)
        #pragma unroll
        for (int kk = 0; kk < 2; ++kk)
            #pragma unroll
            for (int nt = 0; nt < 4; ++nt) {
                int f = ntq * 64 + nt * 16 + l15;
                Bc[ky][kk][nt] = *(const bf16x8*)&Bpack[((((ky * 2 + kk) * 4 + g) * 128 + f) * 8)];
            }
    bf16x8 Bh[4];         // head B-frags [kt]
    #pragma unroll
    for (int kt = 0; kt < 4; ++kt)
        Bh[kt] = *(const bf16x8*)&Whead[(((label * 4 + kt) * 4 + g) * 16 + l15) * 8];

    __syncthreads();  // xin fully staged

    // ---- 8 chunks of 128 spatial positions (4 y-rows each) ----
    for (int chunk = 0; chunk < 8; ++chunk) {
        f32x4 acc[4][4];  // [mtl][nt]
        #pragma unroll
        for (int i = 0; i < 4; ++i)
            #pragma unroll
            for (int j = 0; j < 4; ++j)
                acc[i][j] = f32x4{0.f, 0.f, 0.f, 0.f};

        // conv: 4 mtiles x 4 ntiles x (3 ky * 2 kk) MFMAs
        #pragma unroll
        for (int mtl = 0; mtl < 4; ++mtl) {
            const int mt = mtq * 4 + mtl;              // 0..7 within chunk
            const int y  = chunk * 4 + (mt >> 1);      // output y-row
            const int x0 = (mt & 1) * 16;
            uint64_t a0[3][2][2];
            #pragma unroll
            for (int ky = 0; ky < 3; ++ky) {
                const int pos = (y + ky) * 34 + x0 + l15;   // padded coords
                const uint64_t* ap = (const uint64_t*)&xin[pos * 20 + g * 8];
                a0[ky][0][0] = ap[0]; a0[ky][0][1] = ap[1];  // k 0..31 slice
                a0[ky][1][0] = ap[8]; a0[ky][1][1] = ap[9];  // k 32..63 slice
            }
            #pragma unroll
            for (int ky = 0; ky < 3; ++ky)
                #pragma unroll
                for (int kk = 0; kk < 2; ++kk) {
                    union { uint64_t u[2]; bf16x8 v; } A;
                    A.u[0] = a0[ky][kk][0];
                    A.u[1] = a0[ky][kk][1];
                    #pragma unroll
                    for (int nt = 0; nt < 4; ++nt)
                        acc[mtl][nt] = __builtin_amdgcn_mfma_f32_16x16x32_bf16(
                            A.v, Bc[ky][kk][nt], acc[mtl][nt], 0, 0, 0);
                }
        }

        __syncthreads();  // previous chunk's head phase done reading xlds

        // epilogue: bias+relu+mask, f32->bf16, paired b32 writes into xlds[p][f]
        #pragma unroll
        for (int mtl = 0; mtl < 4; ++mtl) {
            const int mt    = mtq * 4 + mtl;
            const int pbase = mt * 16 + g * 4;   // row within chunk
            const float4 m4 = *(const float4*)&maskings[(size_t)b * 1024 + chunk * 128 + pbase];
            const float mm[4] = {m4.x, m4.y, m4.z, m4.w};
            #pragma unroll
            for (int nt = 0; nt < 4; ++nt) {
                const int f  = ntq * 64 + nt * 16 + l15;
                const int fp = f & ~1;
                float xv[4];
                #pragma unroll
                for (int j = 0; j < 4; ++j)
                    xv[j] = fmaxf(acc[mtl][nt][j] + cb[nt], 0.f) * mm[j];
                float xo[4];
                #pragma unroll
                for (int j = 0; j < 4; ++j) xo[j] = __shfl_xor(xv[j], 1, 64);
                uint32_t w0, w1; int r0, r1;
                if (!(l15 & 1)) {   // even feature lane: rows 0,1 of the quad
                    w0 = (uint32_t)f2bf(xv[0]) | ((uint32_t)f2bf(xo[0]) << 16); r0 = 0;
                    w1 = (uint32_t)f2bf(xv[1]) | ((uint32_t)f2bf(xo[1]) << 16); r1 = 1;
                } else {            // odd feature lane: rows 2,3
                    w0 = (uint32_t)f2bf(xo[2]) | ((uint32_t)f2bf(xv[2]) << 16); r0 = 2;
                    w1 = (uint32_t)f2bf(xo[3]) | ((uint32_t)f2bf(xv[3]) << 16); r1 = 3;
                }
                *(uint32_t*)&xlds[(pbase + r0) * XLDS_STRIDE + fp] = w0;
                *(uint32_t*)&xlds[(pbase + r1) * XLDS_STRIDE + fp] = w1;
            }
        }

        __syncthreads();  // xlds ready

        // head GEMM: each wave does 2 mtiles; K=128 = 4 kt
        #pragma unroll
        for (int mh = 0; mh < 2; ++mh) {
            const int mt = w * 2 + mh;
            f32x4 hacc = f32x4{0.f, 0.f, 0.f, 0.f};
            #pragma unroll
            for (int kt = 0; kt < 4; ++kt) {
                const bf16x8* ax = (const bf16x8*)&xlds[(mt * 16 + l15) * XLDS_STRIDE + kt * 32 + g * 8];
                hacc = __builtin_amdgcn_mfma_f32_16x16x32_bf16(*ax, Bh[kt], hacc, 0, 0, 0);
            }
            const int a = l15;  // action
            const size_t prow = (size_t)b * 1024 + chunk * 128 + mt * 16 + g * 4;
            #pragma unroll
            for (int j = 0; j < 4; ++j) {
                const float v = hacc[j] + hbias;
                const size_t pos = prow + j;
                if (a < NUNIT) out[pos * NUNIT + a] = v;
                else           out[(size_t)BATCH * 1024 * NUNIT + pos * (KACT - NUNIT) + (a - NUNIT)] = v;
            }
        }
    }
}

extern "C" void kernel_launch(void* const* d_in, const int* in_sizes, int n_in,
                              void* d_out, int out_size, void* d_ws, size_t ws_size,
                              hipStream_t stream) {
    const float* states   = (const float*)d_in[0];
    const int*   labels   = (const int*)d_in[1];
    const float* maskings = (const float*)d_in[2];
    const float* conv_w   = (const float*)d_in[3];
    const float* conv_b   = (const float*)d_in[4];
    const float* W_all    = (const float*)d_in[5];
    const float* b_all    = (const float*)d_in[6];
    float* out = (float*)d_out;

    uint16_t* Bpack = (uint16_t*)d_ws;
    uint16_t* Whead = Bpack + BPACK_ELEMS;

    repack_kernel<<<(BPACK_ELEMS + WHEAD_ELEMS + 255) / 256, 256, 0, stream>>>(
        conv_w, W_all, Bpack, Whead);
    fused_mfma_kernel<<<BATCH, 256, 0, stream>>>(
        states, labels, maskings, conv_b, b_all, Bpack, Whead, out);
}